// Round 2
// baseline (93927.838 us; speedup 1.0000x reference)
//
#include <hip/hip_runtime.h>
#include <math.h>

#define T_SEQ 2048
#define BATCH 16
#define CH_T  256              // timesteps per chunk
#define CH_M  (CH_T*BATCH)     // 4096 rows per chunk
#define NCHUNK (T_SEQ/CH_T)    // 8
#define SCALE_K 0.125f         // 1/sqrt(H/NH) = 1/sqrt(64)
#define NWG_S 128              // workgroups in sLSTM cooperative kernel
#define SPIN_LIMIT 300000      // cumulative spin budget per thread (hang guard)

// ---------------------------------------------------------------------------
// Common tiled f32 GEMM body:  C[128,128] tile = act( A-tile @ W-tile^T ).
// A rows from Ap (K-major), W rows from Wp (K-major), writes Cp (ldc row
// stride, pre-offset to the tile's top-left). 256 threads, 8x8 micro-tile.
// ---------------------------------------------------------------------------
template<bool SILU>
__device__ __forceinline__ void gemm_body(const float* __restrict__ Ap,
                                          const float* __restrict__ Wp,
                                          float* __restrict__ Cp,
                                          int K, int ldc)
{
  __shared__ float As[16][132];
  __shared__ float Ws[16][132];
  const int tid = threadIdx.x;
  const int tx = tid & 15, ty = tid >> 4;
  float acc[8][8] = {};
  for (int k0 = 0; k0 < K; k0 += 16) {
#pragma unroll
    for (int i = 0; i < 2; ++i) {
      int idx = tid + i * 256;           // 0..511
      int r = idx >> 2, kq = idx & 3;    // row 0..127, k-quad 0..3
      float4 av = *(const float4*)(Ap + (size_t)r * K + k0 + kq * 4);
      float4 wv = *(const float4*)(Wp + (size_t)r * K + k0 + kq * 4);
      As[kq*4+0][r] = av.x; As[kq*4+1][r] = av.y;
      As[kq*4+2][r] = av.z; As[kq*4+3][r] = av.w;
      Ws[kq*4+0][r] = wv.x; Ws[kq*4+1][r] = wv.y;
      Ws[kq*4+2][r] = wv.z; Ws[kq*4+3][r] = wv.w;
    }
    __syncthreads();
#pragma unroll
    for (int kk = 0; kk < 16; ++kk) {
      float a[8], b[8];
      *(float4*)&a[0] = *(const float4*)&As[kk][ty*8];
      *(float4*)&a[4] = *(const float4*)&As[kk][ty*8+4];
      *(float4*)&b[0] = *(const float4*)&Ws[kk][tx*8];
      *(float4*)&b[4] = *(const float4*)&Ws[kk][tx*8+4];
#pragma unroll
      for (int i = 0; i < 8; ++i)
#pragma unroll
        for (int j = 0; j < 8; ++j)
          acc[i][j] = fmaf(a[i], b[j], acc[i][j]);
    }
    __syncthreads();
  }
#pragma unroll
  for (int i = 0; i < 8; ++i) {
    float* Cr = Cp + (size_t)(ty*8 + i) * ldc + tx*8;
#pragma unroll
    for (int j0 = 0; j0 < 8; j0 += 4) {
      float4 v;
      v.x = acc[i][j0+0]; v.y = acc[i][j0+1];
      v.z = acc[i][j0+2]; v.w = acc[i][j0+3];
      if (SILU) {
        v.x = v.x / (1.f + expf(-v.x));
        v.y = v.y / (1.f + expf(-v.y));
        v.z = v.z / (1.f + expf(-v.z));
        v.w = v.w / (1.f + expf(-v.w));
      }
      *(float4*)(Cr + j0) = v;
    }
  }
}

template<bool SILU>
__global__ __launch_bounds__(256, 2) void gemm_nt(
    const float* __restrict__ A, const float* __restrict__ W,
    float* __restrict__ C, int K, int ldc)
{
  const int bn = blockIdx.x, bm = blockIdx.y;
  gemm_body<SILU>(A + (size_t)bm * 128 * K,
                  W + (size_t)bn * 128 * K,
                  C + (size_t)bm * 128 * ldc + bn * 128, K, ldc);
}

// Fused q|k|v|gates GEMM: A [M,1024] x {Wq,Wk,Wv [512,1024], Wg [1536,1024]}
// -> C [M,3072] with column layout [q|k|v|g].
__global__ __launch_bounds__(256, 2) void gemm_qkvg(
    const float* __restrict__ A,
    const float* __restrict__ Wq, const float* __restrict__ Wk,
    const float* __restrict__ Wv, const float* __restrict__ Wg,
    float* __restrict__ C)
{
  const int bn = blockIdx.x, bm = blockIdx.y;   // bn 0..23
  const float* W; int wrow, ccol;
  if (bn < 4)       { W = Wq; wrow = bn * 128;        ccol = bn * 128; }
  else if (bn < 8)  { W = Wk; wrow = (bn - 4) * 128;  ccol = 512  + (bn - 4) * 128; }
  else if (bn < 12) { W = Wv; wrow = (bn - 8) * 128;  ccol = 1024 + (bn - 8) * 128; }
  else              { W = Wg; wrow = (bn - 12) * 128; ccol = 1536 + (bn - 12) * 128; }
  gemm_body<false>(A + (size_t)bm * 128 * 1024,
                   W + (size_t)wrow * 1024,
                   C + (size_t)bm * 128 * 3072 + ccol, 1024, 3072);
}

// ---------------------------------------------------------------------------
// mLSTM elementwise scan over one T-chunk. z: [CH_M, 3072] = [q|k|v|i|f|o].
// One thread per (b, ch) channel; 4-deep load ring hides L2/L3 latency.
// State (c,n,m) persists in `st` ([3][8192]) across chunks (memset at t=0).
// ---------------------------------------------------------------------------
__global__ __launch_bounds__(64) void mlstm_scan(
    const float* __restrict__ z, const float* __restrict__ bg,
    float* __restrict__ hout, float* __restrict__ st, int nsteps)
{
  const int gt = blockIdx.x * 64 + threadIdx.x;   // 0..8191
  const int b = gt >> 9, hc = gt & 511;
  const float bi = bg[hc], bf = bg[512 + hc], bo = bg[1024 + hc];
  float c = st[gt], n = st[8192 + gt], m = st[16384 + gt];
  const float* zp = z + (size_t)b * 3072 + hc;
  float* hp = hout + (size_t)b * 512 + hc;
  float rq[4], rk[4], rv[4], ri[4], rf[4], ro[4];
#pragma unroll
  for (int d = 0; d < 4; ++d) {
    const float* p = zp + (size_t)d * BATCH * 3072;
    rq[d] = p[0];    rk[d] = p[512];  rv[d] = p[1024];
    ri[d] = p[1536]; rf[d] = p[2048]; ro[d] = p[2560];
  }
  for (int t = 0; t < nsteps; t += 4) {
#pragma unroll
    for (int u = 0; u < 4; ++u) {
      const int tt = t + u;
      float q = rq[u], k = rk[u] * SCALE_K, v = rv[u];
      float it = ri[u] + bi, ft = rf[u] + bf, ot = ro[u] + bo;
      if (tt + 4 < nsteps) {                       // refill ring slot u
        const float* p = zp + (size_t)(tt + 4) * BATCH * 3072;
        rq[u] = p[0];    rk[u] = p[512];  rv[u] = p[1024];
        ri[u] = p[1536]; rf[u] = p[2048]; ro[u] = p[2560];
      }
      float m2 = fmaxf(ft + m, it);
      float i  = expf(it - m2);
      float f  = expf(ft + m - m2);
      c = f * c + i * (v * k);
      n = f * n + i * k;
      m = m2;
      float hv = (1.f / (1.f + expf(-ot))) * (c * q) / fmaxf(fabsf(n * q), 1.f);
      hp[(size_t)tt * BATCH * 512] = hv;
    }
  }
  st[gt] = c; st[8192 + gt] = n; st[16384 + gt] = m;
}

// ---------------------------------------------------------------------------
// sLSTM persistent cooperative kernel over one T-chunk. 128 WGs x 256 thr.
// WG w owns 16 gate columns (4 gates x 4 channels). R staged in LDS once.
// Cross-WG h exchange via agent-scope atomics + flag-array barrier
// (double-buffered h, absolute-step flag values monotone across chunks).
// Bounded spin converts any barrier failure into a fast wrong answer
// instead of a hung container.
// ---------------------------------------------------------------------------
__global__ __launch_bounds__(256, 1) void slstm_seq(
    const float* __restrict__ pre,   // [CH_M, 2048] x@W^T (no bias)
    const float* __restrict__ R,     // [2048, 512]
    const float* __restrict__ bias,  // [2048]
    float* __restrict__ hout,        // [CH_M, 512]
    float* hstate,                   // 2*8192 double buffer (persist)
    unsigned* flags,                 // NWG_S (persist, monotone)
    float* sstate,                   // [3][8192] c,n,m (persist)
    int base, int nsteps)
{
  const int w = blockIdx.x;
  const int tid = threadIdx.x;
  const int lane = tid & 63;
  const int wv = tid >> 6;

  __shared__ float Rl[16][516];
  __shared__ float hl[16][516];
  __shared__ float gl[16][17];

  for (int idx = tid; idx < 16 * 128; idx += 256) {   // stage R rows once
    int j = idx >> 7, k4 = idx & 127;
    int col = (j >> 2) * 512 + w * 4 + (j & 3);
    ((float4*)&Rl[j][0])[k4] = ((const float4*)(R + (size_t)col * 512))[k4];
  }

  const int cb  = lane & 15;                    // batch
  const int cjj = wv * 4 + (lane >> 4);         // local gate-col 0..15
  const int ccol = (cjj >> 2) * 512 + w * 4 + (cjj & 3);
  const float cbias = bias[ccol];

  const int sb = tid & 15, sc = tid >> 4;       // state mapping (tid<64)
  const int sch = w * 4 + sc;
  float st_c = 0.f, st_n = 0.f, st_m = 0.f;
  if (tid < 64) {
    int si = sb * 512 + sch;
    st_c = sstate[si]; st_n = sstate[8192 + si]; st_m = sstate[16384 + si];
  }
  int spins = 0;
  __syncthreads();

  for (int t = 0; t < nsteps; ++t) {
    const int ta = base + t;
    float* hrd = hstate + (ta & 1) * 8192;
    float* hwr = hstate + ((ta + 1) & 1) * 8192;

    float prev = pre[(size_t)(t * BATCH + cb) * 2048 + ccol];  // early issue

    for (int idx = tid; idx < 8192; idx += 256) {   // h_prev -> LDS
      ((float*)hl)[(idx >> 9) * 516 + (idx & 511)] =
          __hip_atomic_load(hrd + idx, __ATOMIC_RELAXED,
                            __HIP_MEMORY_SCOPE_AGENT);
    }
    __syncthreads();

    float acc = 0.f;
    const float4* hp4 = (const float4*)&hl[cb][0];
    const float4* rp4 = (const float4*)&Rl[cjj][0];
#pragma unroll 16
    for (int k4 = 0; k4 < 128; ++k4) {
      float4 a = hp4[k4], r = rp4[k4];
      acc = fmaf(a.x, r.x, acc); acc = fmaf(a.y, r.y, acc);
      acc = fmaf(a.z, r.z, acc); acc = fmaf(a.w, r.w, acc);
    }
    gl[cjj][cb] = acc + prev + cbias;
    __syncthreads();

    if (tid < 64) {
      float it = gl[sc][sb],      ft = gl[4 + sc][sb];
      float zt = gl[8 + sc][sb],  ot = gl[12 + sc][sb];
      float m2 = fmaxf(ft + st_m, it);
      float i  = expf(it - m2);
      float f  = expf(ft + st_m - m2);
      st_c = f * st_c + i * tanhf(zt);
      st_n = f * st_n + i;
      st_m = m2;
      float hv = (1.f / (1.f + expf(-ot))) * st_c / st_n;
      __hip_atomic_store(hwr + sb * 512 + sch, hv, __ATOMIC_RELAXED,
                         __HIP_MEMORY_SCOPE_AGENT);
      hout[(size_t)(t * BATCH + sb) * 512 + sch] = hv;
    }
    __syncthreads();   // drains vmem before the release below

    if (tid == 0)
      __hip_atomic_store(&flags[w], (unsigned)(ta + 1), __ATOMIC_RELEASE,
                         __HIP_MEMORY_SCOPE_AGENT);
    int my_to = 0;
    if (tid < NWG_S) {
      while (__hip_atomic_load(&flags[tid], __ATOMIC_ACQUIRE,
                               __HIP_MEMORY_SCOPE_AGENT) < (unsigned)(ta + 1)) {
        __builtin_amdgcn_s_sleep(1);
        if (++spins > SPIN_LIMIT) { my_to = 1; break; }
      }
    }
    if (__syncthreads_or(my_to)) break;   // uniform bail-out on timeout
  }

  if (tid < 64) {
    int si = sb * 512 + sch;
    sstate[si] = st_c; sstate[8192 + si] = st_n; sstate[16384 + si] = st_m;
  }
}

// ---------------------------------------------------------------------------
extern "C" void kernel_launch(void* const* d_in, const int* in_sizes, int n_in,
                              void* d_out, int out_size, void* d_ws, size_t ws_size,
                              hipStream_t stream) {
  const float* x    = (const float*)d_in[0];
  const float* Wup0 = (const float*)d_in[1];
  const float* Wq0  = (const float*)d_in[2];
  const float* Wk0  = (const float*)d_in[3];
  const float* Wv0  = (const float*)d_in[4];
  const float* Wg0  = (const float*)d_in[5];
  const float* bg0  = (const float*)d_in[6];
  const float* Ws1  = (const float*)d_in[7];
  const float* Rs1  = (const float*)d_in[8];
  const float* bs1  = (const float*)d_in[9];
  const float* Wup2 = (const float*)d_in[10];
  const float* Wq2  = (const float*)d_in[11];
  const float* Wk2  = (const float*)d_in[12];
  const float* Wv2  = (const float*)d_in[13];
  const float* Wg2  = (const float*)d_in[14];
  const float* bg2  = (const float*)d_in[15];
  const float* Ws3  = (const float*)d_in[16];
  const float* Rs3  = (const float*)d_in[17];
  const float* bs3  = (const float*)d_in[18];
  float* out = (float*)d_out;

  // ---- workspace layout (floats), ~84.4 MB total ----
  float* ws   = (float*)d_ws;
  float* up_c = ws;                        // CH_M*1024 =  4,194,304
  float* z_c  = up_c + 4194304;            // CH_M*3072 = 12,582,912 (pre aliases)
  float* h0_c = z_c + 12582912;            // CH_M*512  =  2,097,152 (also h2)
  float* h1_c = h0_c + 2097152;            // CH_M*512  =  2,097,152
  float* ctrl = h1_c + 2097152;            // persistent control region:
  float* mst0 = ctrl;                      //  3*8192 mLSTM-0 state
  float* mst2 = mst0 + 24576;              //  3*8192 mLSTM-2 state
  float* sst1 = mst2 + 24576;              //  3*8192 sLSTM-1 state
  float* sst3 = sst1 + 24576;              //  3*8192 sLSTM-3 state
  float* hb1  = sst3 + 24576;              //  2*8192 sLSTM-1 h dbuf
  float* hb3  = hb1 + 16384;               //  2*8192 sLSTM-3 h dbuf
  unsigned* fl1 = (unsigned*)(hb3 + 16384);//  128 flags
  // fl3 = fl1 + 128
  const size_t ctrl_bytes = (4 * 24576 + 2 * 16384) * sizeof(float)
                          + 2 * NWG_S * sizeof(unsigned);
  hipMemsetAsync(ctrl, 0, ctrl_bytes, stream);   // zero states/h-bufs/flags

  unsigned* fl3 = fl1 + NWG_S;
  dim3 blk(256);
  for (int c = 0; c < NCHUNK; ++c) {
    const size_t r0 = (size_t)c * CH_M;          // row offset of this chunk
    const int base = c * CH_T;                   // absolute step offset
    // ---- layer 0 (mLSTM) ----
    gemm_nt<true ><<<dim3( 8, 32), blk, 0, stream>>>(x + r0 * 512, Wup0, up_c, 512, 1024);
    gemm_qkvg     <<<dim3(24, 32), blk, 0, stream>>>(up_c, Wq0, Wk0, Wv0, Wg0, z_c);
    mlstm_scan    <<<128, 64, 0, stream>>>(z_c, bg0, h0_c, mst0, CH_T);
    // ---- layer 1 (sLSTM) ----
    gemm_nt<false><<<dim3(16, 32), blk, 0, stream>>>(h0_c, Ws1, z_c, 512, 2048);
    slstm_seq     <<<NWG_S, blk, 0, stream>>>(z_c, Rs1, bs1, h1_c, hb1, fl1, sst1, base, CH_T);
    // ---- layer 2 (mLSTM) ----
    gemm_nt<true ><<<dim3( 8, 32), blk, 0, stream>>>(h1_c, Wup2, up_c, 512, 1024);
    gemm_qkvg     <<<dim3(24, 32), blk, 0, stream>>>(up_c, Wq2, Wk2, Wv2, Wg2, z_c);
    mlstm_scan    <<<128, 64, 0, stream>>>(z_c, bg2, h0_c, mst2, CH_T);
    // ---- layer 3 (sLSTM) -> final output rows ----
    gemm_nt<false><<<dim3(16, 32), blk, 0, stream>>>(h0_c, Ws3, z_c, 512, 2048);
    slstm_seq     <<<NWG_S, blk, 0, stream>>>(z_c, Rs3, bs3, out + r0 * 512, hb3, fl3, sst3, base, CH_T);
  }
}